// Round 3
// baseline (348.379 us; speedup 1.0000x reference)
//
#include <hip/hip_runtime.h>

// out[n,c,j,i] = x[n, c, clamp(j + sy - 4, 0, 127), clamp(i + sx - 4, 0, 127)]
// (sx, sy) = shift[n]. Pure memory-bound shifted copy.
//
// This version: one block per (n,c) 128x128 plane (3072 blocks, 64KB each),
// 16-row loop per thread. dx is block-uniform -> scalar switch into a
// template<DX> body; edge columns are compile-time register selects from the
// aligned vector load (no scalar loads, no divergent VMEM at all).

constexpr int Himg = 128;
constexpr int Cimg = 12;
constexpr int PADc = 4;

using f4 = __attribute__((ext_vector_type(4))) float;

template <int DX>
__device__ __forceinline__ void shift_plane(const float* __restrict__ src,
                                            float* __restrict__ dstp,
                                            int col4, int jrow0, int dy)
{
    if constexpr (DX == 0) {
        const int q = col4 * 4;
#pragma unroll
        for (int it = 0; it < 16; ++it) {
            const int j = jrow0 + it * 8;
            int sj = j + dy; sj = sj < 0 ? 0 : (sj > Himg - 1 ? Himg - 1 : sj);
            f4 v = *reinterpret_cast<const f4*>(src + sj * Himg + q);
            __builtin_nontemporal_store(v, reinterpret_cast<f4*>(dstp + j * Himg));
        }
    } else {
        constexpr int R = DX & 3;               // 0..3, compile-time
        const int q = col4 * 4 + (DX - R);      // 16B-aligned source base
        int qa = q;     if (qa < 0) qa = 0; if (qa > Himg - 4) qa = Himg - 4;
        int qb = q + 4; if (qb < 0) qb = 0; if (qb > Himg - 4) qb = Himg - 4;
        const bool edge = (DX > 0) ? (col4 == 31) : (col4 == 0);

        // edge-lane gather indices, all compile-time:
        //   DX>0 (col4==31, A at col 124): out[e] = A[min(DX+e,3)]
        //   DX<0 (col4==0,  A at col 0)  : out[e] = A[max(DX+e,0)]
#define EIDX(e) (DX > 0 ? ((DX + (e)) > 3 ? 3 : (DX + (e))) \
                        : ((DX + (e)) < 0 ? 0 : (DX + (e))))
#pragma unroll
        for (int it = 0; it < 16; ++it) {
            const int j = jrow0 + it * 8;
            int sj = j + dy; sj = sj < 0 ? 0 : (sj > Himg - 1 ? Himg - 1 : sj);
            const float* row = src + sj * Himg;
            const f4 A = *reinterpret_cast<const f4*>(row + qa);
            f4 vi;
            if constexpr (R != 0) {
                const f4 B = *reinterpret_cast<const f4*>(row + qb);
                // interior blend: out[e] = concat(A,B)[R+e], indices compile-time
                vi[0] = (R + 0 < 4) ? A[(R + 0) & 3] : B[(R + 0) & 3];
                vi[1] = (R + 1 < 4) ? A[(R + 1) & 3] : B[(R + 1) & 3];
                vi[2] = (R + 2 < 4) ? A[(R + 2) & 3] : B[(R + 2) & 3];
                vi[3] = (R + 3 < 4) ? A[(R + 3) & 3] : B[(R + 3) & 3];
            } else {
                vi = A;    // DX = +/-4: single aligned load suffices interior
            }
            f4 ve;
            ve[0] = A[EIDX(0)]; ve[1] = A[EIDX(1)];
            ve[2] = A[EIDX(2)]; ve[3] = A[EIDX(3)];
            f4 v;
            v[0] = edge ? ve[0] : vi[0];
            v[1] = edge ? ve[1] : vi[1];
            v[2] = edge ? ve[2] : vi[2];
            v[3] = edge ? ve[3] : vi[3];
            __builtin_nontemporal_store(v, reinterpret_cast<f4*>(dstp + j * Himg));
        }
#undef EIDX
    }
}

__global__ __launch_bounds__(256) void random_shift_kernel(
    const float* __restrict__ x,
    const int* __restrict__ shift,
    float* __restrict__ out)
{
    const int cc  = blockIdx.x;        // channel 0..11
    const int n   = blockIdx.y;        // image 0..255
    const int tid = threadIdx.x;
    const int col4  = tid & 31;        // float4 slot within a row
    const int jrow0 = tid >> 5;        // 0..7

    // block-uniform shift -> SGPR -> scalar switch below
    const int sx = __builtin_amdgcn_readfirstlane(shift[2 * n]);
    const int sy = __builtin_amdgcn_readfirstlane(shift[2 * n + 1]);
    const int dx = sx - PADc;          // [-4, 4]
    const int dy = sy - PADc;

    const size_t plane = (size_t)(n * Cimg + cc) * (Himg * Himg);
    const float* __restrict__ src  = x   + plane;
    float* __restrict__       dstp = out + plane + col4 * 4;

    switch (dx) {
        case -4: shift_plane<-4>(src, dstp, col4, jrow0, dy); break;
        case -3: shift_plane<-3>(src, dstp, col4, jrow0, dy); break;
        case -2: shift_plane<-2>(src, dstp, col4, jrow0, dy); break;
        case -1: shift_plane<-1>(src, dstp, col4, jrow0, dy); break;
        case  0: shift_plane< 0>(src, dstp, col4, jrow0, dy); break;
        case  1: shift_plane< 1>(src, dstp, col4, jrow0, dy); break;
        case  2: shift_plane< 2>(src, dstp, col4, jrow0, dy); break;
        case  3: shift_plane< 3>(src, dstp, col4, jrow0, dy); break;
        default: shift_plane< 4>(src, dstp, col4, jrow0, dy); break;
    }
}

extern "C" void kernel_launch(void* const* d_in, const int* in_sizes, int n_in,
                              void* d_out, int out_size, void* d_ws, size_t ws_size,
                              hipStream_t stream) {
    const float* x     = (const float*)d_in[0];
    const int*   shift = (const int*)d_in[1];
    float*       out   = (float*)d_out;

    dim3 grid(Cimg, 256);   // one block per (channel, image) plane
    random_shift_kernel<<<grid, 256, 0, stream>>>(x, shift, out);
}